// Round 3
// baseline (319.998 us; speedup 1.0000x reference)
//
#include <hip/hip_runtime.h>

#define LN_EPS 1e-5f
#define ROWS 2

typedef float v2f __attribute__((ext_vector_type(2)));

__device__ __forceinline__ float fast_rcp(float x) {
    return __builtin_amdgcn_rcpf(x);
}

__device__ __forceinline__ v2f ld2(const float* p) {
    return *reinterpret_cast<const v2f*>(p);
}

__device__ __forceinline__ v2f pk_fma(v2f a, v2f b, v2f c) {
    return __builtin_elementwise_fma(a, b, c);
}

__device__ __forceinline__ v2f splat(float s) {
    v2f r = {s, s};
    return r;
}

__device__ __forceinline__ float silu_f(float x) {
    // x * sigmoid(x); exp overflow -> inf -> rcp -> 0 (correct limit)
    return x * fast_rcp(1.0f + __expf(-x));
}

__device__ __forceinline__ v2f silu2(v2f a) {
    v2f r;
    r.x = silu_f(a.x);
    r.y = silu_f(a.y);
    return r;
}

__device__ __forceinline__ float tanh_f(float x) {
    float ax = fabsf(x);
    float t = __expf(-2.0f * ax);
    float r = (1.0f - t) * fast_rcp(1.0f + t);
    return copysignf(r, x);
}

__device__ __forceinline__ float softplus_f(float x) {
    float e = __expf(-fabsf(x));
    return fmaxf(x, 0.0f) + __logf(1.0f + e);
}

// Two-row expert, weight loads shared across rows.
// w1: (16,24) row-major, w2: (24,16) row-major.
__device__ __forceinline__ void expert_pk(const float xv[ROWS][16],
                                          const float* __restrict__ w1,
                                          const float* __restrict__ b1,
                                          const float* __restrict__ g,
                                          const float* __restrict__ bn,
                                          const float* __restrict__ w2,
                                          const float* __restrict__ b2,
                                          v2f outv[ROWS][8]) {
    v2f hh[ROWS][12];
#pragma unroll
    for (int j = 0; j < 12; ++j) {
        v2f b = ld2(b1 + 2 * j);
#pragma unroll
        for (int r = 0; r < ROWS; ++r) hh[r][j] = b;
    }
#pragma unroll
    for (int k = 0; k < 16; ++k) {
#pragma unroll
        for (int j = 0; j < 12; ++j) {
            v2f w = ld2(w1 + k * 24 + 2 * j);
#pragma unroll
            for (int r = 0; r < ROWS; ++r)
                hh[r][j] = pk_fma(splat(xv[r][k]), w, hh[r][j]);
        }
    }
    float mu[ROWS], rstd[ROWS];
#pragma unroll
    for (int r = 0; r < ROWS; ++r) {
        v2f sv = hh[r][0];
#pragma unroll
        for (int j = 1; j < 12; ++j) sv = sv + hh[r][j];
        mu[r] = (sv.x + sv.y) * (1.0f / 24.0f);
        v2f muv = splat(mu[r]);
        v2f vv = {0.0f, 0.0f};
#pragma unroll
        for (int j = 0; j < 12; ++j) {
            v2f d = hh[r][j] - muv;
            vv = pk_fma(d, d, vv);
        }
        rstd[r] = rsqrtf(fmaf(vv.x + vv.y, 1.0f / 24.0f, LN_EPS));
    }
#pragma unroll
    for (int j = 0; j < 12; ++j) {
        v2f gv = ld2(g + 2 * j);
        v2f bv = ld2(bn + 2 * j);
#pragma unroll
        for (int r = 0; r < ROWS; ++r) {
            v2f n = pk_fma((hh[r][j] - splat(mu[r])) * splat(rstd[r]), gv, bv);
            hh[r][j] = silu2(n);
        }
    }
#pragma unroll
    for (int j = 0; j < 8; ++j) {
        v2f b = ld2(b2 + 2 * j);
#pragma unroll
        for (int r = 0; r < ROWS; ++r) outv[r][j] = b;
    }
#pragma unroll
    for (int k = 0; k < 24; ++k) {
        float hk[ROWS];
#pragma unroll
        for (int r = 0; r < ROWS; ++r)
            hk[r] = (k & 1) ? hh[r][k >> 1].y : hh[r][k >> 1].x;
#pragma unroll
        for (int j = 0; j < 8; ++j) {
            v2f w = ld2(w2 + k * 16 + 2 * j);
#pragma unroll
            for (int r = 0; r < ROWS; ++r)
                outv[r][j] = pk_fma(splat(hk[r]), w, outv[r][j]);
        }
    }
#pragma unroll
    for (int j = 0; j < 8; ++j)
#pragma unroll
        for (int r = 0; r < ROWS; ++r) outv[r][j] = silu2(outv[r][j]);
}

__global__ __launch_bounds__(256) void moe_fused_kernel(
    const float* __restrict__ x,
    const float* __restrict__ gw1, const float* __restrict__ gb1,
    const float* __restrict__ gw2, const float* __restrict__ gb2,
    const float* __restrict__ e1w1, const float* __restrict__ e1b1,
    const float* __restrict__ e1g, const float* __restrict__ e1bn,
    const float* __restrict__ e1w2, const float* __restrict__ e1b2,
    const float* __restrict__ e2w1, const float* __restrict__ e2b1,
    const float* __restrict__ e2g, const float* __restrict__ e2bn,
    const float* __restrict__ e2w2, const float* __restrict__ e2b2,
    const float* __restrict__ tw, const float* __restrict__ tb,
    const float* __restrict__ sw, const float* __restrict__ sb,
    const float* __restrict__ hw, const float* __restrict__ hb,
    float* __restrict__ out, int nrows) {
    int row0 = (blockIdx.x * blockDim.x + threadIdx.x) * ROWS;
    if (row0 >= nrows) return;

    // ---- load x rows (clamp OOB row to last valid; its output is masked) ----
    float xv[ROWS][16];
#pragma unroll
    for (int r = 0; r < ROWS; ++r) {
        int rr = row0 + r;
        if (rr >= nrows) rr = nrows - 1;
        const float4* xr = reinterpret_cast<const float4*>(x + (size_t)rr * 16);
#pragma unroll
        for (int i = 0; i < 4; ++i) {
            float4 v = xr[i];
            xv[r][4 * i + 0] = v.x;
            xv[r][4 * i + 1] = v.y;
            xv[r][4 * i + 2] = v.z;
            xv[r][4 * i + 3] = v.w;
        }
    }

    // ---- gate: w0 = sigmoid(l0 - l1), l = tanh(x@gw1+gb1)@gw2+gb2 ----
    v2f ga[ROWS][4];
#pragma unroll
    for (int j = 0; j < 4; ++j) {
        v2f b = ld2(gb1 + 2 * j);
#pragma unroll
        for (int r = 0; r < ROWS; ++r) ga[r][j] = b;
    }
#pragma unroll
    for (int k = 0; k < 16; ++k) {
#pragma unroll
        for (int j = 0; j < 4; ++j) {
            v2f w = ld2(gw1 + k * 8 + 2 * j);
#pragma unroll
            for (int r = 0; r < ROWS; ++r)
                ga[r][j] = pk_fma(splat(xv[r][k]), w, ga[r][j]);
        }
    }
    float gh[ROWS][8];
#pragma unroll
    for (int j = 0; j < 4; ++j)
#pragma unroll
        for (int r = 0; r < ROWS; ++r) {
            gh[r][2 * j + 0] = tanh_f(ga[r][j].x);
            gh[r][2 * j + 1] = tanh_f(ga[r][j].y);
        }
    v2f gl[ROWS];
    {
        v2f b = ld2(gb2);
#pragma unroll
        for (int r = 0; r < ROWS; ++r) gl[r] = b;
    }
#pragma unroll
    for (int k = 0; k < 8; ++k) {
        v2f w = ld2(gw2 + 2 * k);
#pragma unroll
        for (int r = 0; r < ROWS; ++r)
            gl[r] = pk_fma(splat(gh[r][k]), w, gl[r]);
    }
    float w0[ROWS], w1v[ROWS];
#pragma unroll
    for (int r = 0; r < ROWS; ++r) {
        // softmax over 2 logits == sigmoid of the difference
        w0[r] = fast_rcp(1.0f + __expf(gl[r].y - gl[r].x));
        w1v[r] = 1.0f - w0[r];
    }

    // ---- experts ----
    v2f h1[ROWS][8], h2[ROWS][8];
    expert_pk(xv, e1w1, e1b1, e1g, e1bn, e1w2, e1b2, h1);
    expert_pk(xv, e2w1, e2b1, e2g, e2bn, e2w2, e2b2, h2);

    v2f h[ROWS][8];
#pragma unroll
    for (int r = 0; r < ROWS; ++r)
#pragma unroll
        for (int j = 0; j < 8; ++j)
            h[r][j] = pk_fma(splat(w0[r]), h1[r][j], splat(w1v[r]) * h2[r][j]);

    // ---- trunk: silu(h@tw+tb), tw (16,16) ----
    v2f tt[ROWS][8];
#pragma unroll
    for (int j = 0; j < 8; ++j) {
        v2f b = ld2(tb + 2 * j);
#pragma unroll
        for (int r = 0; r < ROWS; ++r) tt[r][j] = b;
    }
#pragma unroll
    for (int k = 0; k < 16; ++k) {
        float hk[ROWS];
#pragma unroll
        for (int r = 0; r < ROWS; ++r)
            hk[r] = (k & 1) ? h[r][k >> 1].y : h[r][k >> 1].x;
#pragma unroll
        for (int j = 0; j < 8; ++j) {
            v2f w = ld2(tw + k * 16 + 2 * j);
#pragma unroll
            for (int r = 0; r < ROWS; ++r)
                tt[r][j] = pk_fma(splat(hk[r]), w, tt[r][j]);
        }
    }
#pragma unroll
    for (int j = 0; j < 8; ++j)
#pragma unroll
        for (int r = 0; r < ROWS; ++r) tt[r][j] = silu2(tt[r][j]);

    // ---- heads ----
    float strain[ROWS];
    v2f hsv[ROWS];
#pragma unroll
    for (int r = 0; r < ROWS; ++r) strain[r] = sb[0];
    {
        v2f b = ld2(hb);
#pragma unroll
        for (int r = 0; r < ROWS; ++r) hsv[r] = b;
    }
#pragma unroll
    for (int k = 0; k < 16; ++k) {
        float swk = sw[k];
        v2f hwk = ld2(hw + 2 * k);
#pragma unroll
        for (int r = 0; r < ROWS; ++r) {
            float tk = (k & 1) ? tt[r][k >> 1].y : tt[r][k >> 1].x;
            strain[r] = fmaf(tk, swk, strain[r]);
            hsv[r] = pk_fma(splat(tk), hwk, hsv[r]);
        }
    }
#pragma unroll
    for (int r = 0; r < ROWS; ++r) {
        int rr = row0 + r;
        if (rr >= nrows) continue;
        float gap = softplus_f(hsv[r].y);
        size_t o = (size_t)rr * 3;
        out[o + 0] = strain[r];
        out[o + 1] = hsv[r].x;            // tensile_raw
        out[o + 2] = hsv[r].x - gap;      // yield_strength
    }
}

extern "C" void kernel_launch(void* const* d_in, const int* in_sizes, int n_in,
                              void* d_out, int out_size, void* d_ws, size_t ws_size,
                              hipStream_t stream) {
    const float* x    = (const float*)d_in[0];
    const float* gw1  = (const float*)d_in[1];
    const float* gb1  = (const float*)d_in[2];
    const float* gw2  = (const float*)d_in[3];
    const float* gb2  = (const float*)d_in[4];
    const float* e1w1 = (const float*)d_in[5];
    const float* e1b1 = (const float*)d_in[6];
    const float* e1g  = (const float*)d_in[7];
    const float* e1bn = (const float*)d_in[8];
    const float* e1w2 = (const float*)d_in[9];
    const float* e1b2 = (const float*)d_in[10];
    const float* e2w1 = (const float*)d_in[11];
    const float* e2b1 = (const float*)d_in[12];
    const float* e2g  = (const float*)d_in[13];
    const float* e2bn = (const float*)d_in[14];
    const float* e2w2 = (const float*)d_in[15];
    const float* e2b2 = (const float*)d_in[16];
    const float* tw   = (const float*)d_in[17];
    const float* tb   = (const float*)d_in[18];
    const float* sw   = (const float*)d_in[19];
    const float* sb   = (const float*)d_in[20];
    const float* hw   = (const float*)d_in[21];
    const float* hb   = (const float*)d_in[22];
    float* out = (float*)d_out;

    int nrows = in_sizes[0] / 16;
    int block = 256;
    int rows_per_block = block * ROWS;
    int grid = (nrows + rows_per_block - 1) / rows_per_block;
    moe_fused_kernel<<<grid, block, 0, stream>>>(
        x, gw1, gb1, gw2, gb2,
        e1w1, e1b1, e1g, e1bn, e1w2, e1b2,
        e2w1, e2b1, e2g, e2bn, e2w2, e2b2,
        tw, tb, sw, sb, hw, hb, out, nrows);
}